// Round 1
// baseline (148.834 us; speedup 1.0000x reference)
//
#include <hip/hip_runtime.h>
#include <math.h>

// HyperbolicLinearAttention: B=4, N=4096, C=6144, H=32, D=64
//   A[d,e] = sum_n k[n,d] v[n,e];  S = softmax_e(A)  (rows sum to 1 over e)
//   out[b,n,h*64+j] = sum_i (q[n,i]*SCALE) * S[j,i]
// x layout: x[b][n][c], c = qkv*2048 + h*64 + d  (q:0, k:2048, v:4096)

#define NN 4096
#define CC 6144
#define QSCALE 0.17677669529663687f  // 32^-0.5
#define NCHUNK 8

typedef __attribute__((ext_vector_type(8))) short bf16x8;
typedef __attribute__((ext_vector_type(4))) float f32x4;

static __device__ __forceinline__ unsigned short f2bf(float f) {
  unsigned u = __float_as_uint(f);
  u = (u + 0x7FFFu + ((u >> 16) & 1u)) >> 16;  // RNE
  return (unsigned short)u;
}

// ---------------- kernel 1: partial A = k^T v via MFMA, bf16 hi/lo split ----------------
// grid = 128 bh * 8 chunks = 1024 blocks, 256 threads (4 waves), 32 KB LDS.
// Transpose is done at the GLOBAL-address level: global_load_lds(size=4) with per-lane
// scattered (but 64B-sector-coalesced: 4 rows x 64 B per instr) addresses lands fp32 data
// in LDS already in MFMA-fragment-linear layout [mt][r][fraglane][j4]. Fragment reads are
// then linear conflict-free ds_read_b128; in-register split k=khi+klo (exact residual),
// 3 MFMA passes (hh, hl, lh) give ~2^-16-relative-accurate fp32 A.
// Wave w stages region mt=nt=w; owns output tiles (mt0+i2, nt0+j2), 2x2 split.
__global__ __launch_bounds__(256, 4) void k1_kv_accum(const float* __restrict__ x,
                                                      float* __restrict__ ws1) {
  __shared__ float lds[2][4096];  // [buf][ A: mt*512 + r*256 + lane*4 + j4 | B: 2048 + same ]

  const int bid = blockIdx.x;
  const int bh = bid >> 3;
  const int chunk = bid & (NCHUNK - 1);
  const int b = bh >> 5, h = bh & 31;
  const int t = threadIdx.x;
  const int lane = t & 63;
  const int w = t >> 6;

  const long long row0 = (long long)b * NN + (long long)chunk * 512;
  const float* kbase = x + row0 * CC + 2048 + h * 64;
  // per-lane scatter: row += lane&3, col += lane>>2; this wave stages col-block w*16
  const float* kl = kbase + (lane & 3) * CC + (lane >> 2) + w * 16;
  const float* vl = kl + 2048;

// stage slab sb (32 rows) into buffer bbv: 16 x global_load_lds(size=4), 16 KB total/block
#define K1_STAGE(sb, bbv)                                                                 \
  do {                                                                                    \
    const float* kp_ = kl + (sb) * 32 * CC;                                               \
    const float* vp_ = vl + (sb) * 32 * CC;                                               \
    _Pragma("unroll") for (int r_ = 0; r_ < 2; ++r_)                                      \
    _Pragma("unroll") for (int sub_ = 0; sub_ < 4; ++sub_) {                              \
      const int ro_ = (sub_ * 8 + r_ * 4) * CC;                                           \
      const int li_ = w * 512 + r_ * 256 + sub_ * 64;                                     \
      __builtin_amdgcn_global_load_lds(                                                   \
          (const __attribute__((address_space(1))) void*)(kp_ + ro_),                     \
          (__attribute__((address_space(3))) void*)&lds[(bbv)][li_], 4, 0, 0);            \
      __builtin_amdgcn_global_load_lds(                                                   \
          (const __attribute__((address_space(1))) void*)(vp_ + ro_),                     \
          (__attribute__((address_space(3))) void*)&lds[(bbv)][2048 + li_], 4, 0, 0);     \
    }                                                                                     \
  } while (0)

// read one fp32 fragment (8 elems/lane, linear b128 x2) and split into bf16 hi/lo frags
#define K1_FRAG(bbv, baseidx, hi8, lo8)                                                   \
  do {                                                                                    \
    const float4 f0_ = *(const float4*)&lds[(bbv)][(baseidx) + lane * 4];                 \
    const float4 f1_ = *(const float4*)&lds[(bbv)][(baseidx) + 256 + lane * 4];           \
    const float ff_[8] = {f0_.x, f0_.y, f0_.z, f0_.w, f1_.x, f1_.y, f1_.z, f1_.w};        \
    _Pragma("unroll") for (int e_ = 0; e_ < 8; ++e_) {                                    \
      const unsigned u_ = __float_as_uint(ff_[e_]);                                       \
      hi8[e_] = (short)(u_ >> 16); /* truncation: residual captured exactly by lo */      \
      const float lof_ = ff_[e_] - __uint_as_float(u_ & 0xFFFF0000u);                     \
      lo8[e_] = (short)(__float_as_uint(lof_) >> 16);                                     \
    }                                                                                     \
  } while (0)

  f32x4 acc[2][2];
#pragma unroll
  for (int i2 = 0; i2 < 2; ++i2)
#pragma unroll
    for (int j2 = 0; j2 < 2; ++j2) acc[i2][j2] = (f32x4){0.f, 0.f, 0.f, 0.f};

  const int mt0 = (w & 1) * 2;
  const int nt0 = (w >> 1) * 2;

  K1_STAGE(0, 0);
  asm volatile("s_waitcnt vmcnt(0)" ::: "memory");
  __syncthreads();

  for (int s = 0; s < 16; ++s) {
    const int bb = s & 1;
    if (s + 1 < 16) K1_STAGE(s + 1, bb ^ 1);

    bf16x8 ah[2], al[2], bh8[2], bl8[2];
#pragma unroll
    for (int i2 = 0; i2 < 2; ++i2) K1_FRAG(bb, (mt0 + i2) * 512, ah[i2], al[i2]);
#pragma unroll
    for (int j2 = 0; j2 < 2; ++j2) K1_FRAG(bb, 2048 + (nt0 + j2) * 512, bh8[j2], bl8[j2]);

#pragma unroll
    for (int i2 = 0; i2 < 2; ++i2)
#pragma unroll
      for (int j2 = 0; j2 < 2; ++j2) {
        acc[i2][j2] = __builtin_amdgcn_mfma_f32_16x16x32_bf16(ah[i2], bh8[j2], acc[i2][j2], 0, 0, 0);
        acc[i2][j2] = __builtin_amdgcn_mfma_f32_16x16x32_bf16(ah[i2], bl8[j2], acc[i2][j2], 0, 0, 0);
        acc[i2][j2] = __builtin_amdgcn_mfma_f32_16x16x32_bf16(al[i2], bh8[j2], acc[i2][j2], 0, 0, 0);
      }

    if (s + 1 < 16) {
      asm volatile("s_waitcnt vmcnt(0)" ::: "memory");
      __syncthreads();
    }
  }

  // write-out: plain row-major A[d][e]. C/D: col=lane&15 -> e, row=(lane>>4)*4+reg -> d.
  float* dst = ws1 + (long long)bid * 4096;
  const int g = lane >> 4, cl = lane & 15;
#pragma unroll
  for (int i2 = 0; i2 < 2; ++i2)
#pragma unroll
    for (int j2 = 0; j2 < 2; ++j2)
#pragma unroll
      for (int r = 0; r < 4; ++r)
        dst[((mt0 + i2) * 16 + g * 4 + r) * 64 + (nt0 + j2) * 16 + cl] = acc[i2][j2][r];
}

// ---------------- kernel 2: reduce chunks + softmax -> bf16 S*QSCALE ----------------
// grid = 128 blocks (one per bh), 256 threads. ws1 is now plain row-major A[d][e].
// Output ws2bf[bh][j*64+i] = bf16(QSCALE * S[j][i])  (row-major, A-operand-ready)
__global__ __launch_bounds__(256) void k2_softmax(const float* __restrict__ ws1,
                                                  unsigned short* __restrict__ ws2bf) {
  const int bh = blockIdx.x;
  __shared__ float Cs[64 * 65];
  __shared__ float Ss[64 * 65];
  const int t = threadIdx.x;
  const float* src = ws1 + (long long)bh * NCHUNK * 4096;
  for (int s0 = t; s0 < 1024; s0 += 256) {  // float4 slots
    float4 sum = {0.f, 0.f, 0.f, 0.f};
#pragma unroll
    for (int c = 0; c < NCHUNK; ++c) {
      const float4 f = *(const float4*)&src[c * 4096 + s0 * 4];
      sum.x += f.x; sum.y += f.y; sum.z += f.z; sum.w += f.w;
    }
    const float se[4] = {sum.x, sum.y, sum.z, sum.w};
#pragma unroll
    for (int e = 0; e < 4; ++e) {
      const int idx = s0 * 4 + e;  // idx = d*64 + col  (row-major from k1)
      Cs[(idx >> 6) * 65 + (idx & 63)] = se[e];
    }
  }
  __syncthreads();
  if (t < 64) {
    const int a = t;
    float m = -3.0e38f;
    for (int c = 0; c < 64; ++c) m = fmaxf(m, Cs[a * 65 + c]);
    float sum = 0.f;
    for (int c = 0; c < 64; ++c) {
      const float e = expf(Cs[a * 65 + c] - m);
      Ss[a * 65 + c] = e;
      sum += e;
    }
    const float inv = QSCALE / sum;
    for (int c = 0; c < 64; ++c) Ss[a * 65 + c] *= inv;
  }
  __syncthreads();
  unsigned short* dst = ws2bf + (long long)bh * 4096;
  for (int idx = t; idx < 4096; idx += 256) {
    const int j = idx >> 6;
    const int i = idx & 63;
    dst[idx] = f2bf(Ss[j * 65 + i]);  // row-major S (row j over i), scaled
  }
}

// ---------------- kernel 3: out = q @ S^T via MFMA, swapped operands ----------------
// grid = 128 bh * 32 tiles = 4096 blocks, 256 threads (4 waves). NO LDS, NO barriers.
// D[m][n] = sum_k A[m,k]*B[n,k] with A = S rows (m=j, k=i), B = q rows (n=row, k=i).
// C/D layout: col = lane&15 -> n (out ROW), row = (lane>>4)*4+reg -> m (out COL)
// => per-lane 4 consecutive out columns = one float4 store per acc tile.
__global__ __launch_bounds__(256) void k3_apply(const float* __restrict__ x,
                                                const unsigned short* __restrict__ ws2bf,
                                                float* __restrict__ out) {
  const int bid = blockIdx.x;
  const int bh = bid >> 5;
  const int tile = bid & 31;
  const int b = bh >> 5, h = bh & 31;
  const int t = threadIdx.x;
  const int lane = t & 63;
  const int w = t >> 6;
  const int bn = lane & 15;
  const int g = lane >> 4;

  // A fragments: S rows from global (L2-hot, 8 KB/bh):
  // afr[mt][kc] : A[m = mt*16 + bn][k-run = kc*32 + g*8 .. +8]
  const unsigned short* mb = ws2bf + (long long)bh * 4096;
  bf16x8 afr[4][2];
#pragma unroll
  for (int mt = 0; mt < 4; ++mt)
#pragma unroll
    for (int kc = 0; kc < 2; ++kc)
      afr[mt][kc] = *(const bf16x8*)(mb + (mt * 16 + bn) * 64 + kc * 32 + g * 8);

  // B fragments: q rows fp32 -> bf16 in registers. Wave w owns n-tiles {2w, 2w+1}.
  const float* qb = x + ((long long)b * NN + tile * 128) * CC + h * 64;
  bf16x8 bfr[2][2];
#pragma unroll
  for (int u = 0; u < 2; ++u) {
    const int nt = w * 2 + u;
#pragma unroll
    for (int kc = 0; kc < 2; ++kc) {
      const float* p = qb + (long long)(nt * 16 + bn) * CC + kc * 32 + g * 8;
      const float4 f0 = *(const float4*)p;
      const float4 f1 = *(const float4*)(p + 4);
      bf16x8 r;
      r[0] = (short)f2bf(f0.x); r[1] = (short)f2bf(f0.y);
      r[2] = (short)f2bf(f0.z); r[3] = (short)f2bf(f0.w);
      r[4] = (short)f2bf(f1.x); r[5] = (short)f2bf(f1.y);
      r[6] = (short)f2bf(f1.z); r[7] = (short)f2bf(f1.w);
      bfr[u][kc] = r;
    }
  }

  f32x4 acc[2][4];
#pragma unroll
  for (int u = 0; u < 2; ++u)
#pragma unroll
    for (int mt = 0; mt < 4; ++mt) acc[u][mt] = (f32x4){0.f, 0.f, 0.f, 0.f};

#pragma unroll
  for (int kc = 0; kc < 2; ++kc)
#pragma unroll
    for (int u = 0; u < 2; ++u)
#pragma unroll
      for (int mt = 0; mt < 4; ++mt)
        acc[u][mt] = __builtin_amdgcn_mfma_f32_16x16x32_bf16(afr[mt][kc], bfr[u][kc],
                                                             acc[u][mt], 0, 0, 0);

  // store: out row = tile*128 + nt*16 + bn, cols h*64 + mt*16 + g*4 .. +4
  const long long rowg = (long long)b * NN + tile * 128;
#pragma unroll
  for (int u = 0; u < 2; ++u) {
    const int nt = w * 2 + u;
    const long long r = rowg + nt * 16 + bn;
#pragma unroll
    for (int mt = 0; mt < 4; ++mt) {
      float* op = out + r * 2048 + h * 64 + mt * 16 + g * 4;
      const float4 o = {acc[u][mt][0], acc[u][mt][1], acc[u][mt][2], acc[u][mt][3]};
      *(float4*)op = o;
    }
  }
}

extern "C" void kernel_launch(void* const* d_in, const int* in_sizes, int n_in,
                              void* d_out, int out_size, void* d_ws, size_t ws_size,
                              hipStream_t stream) {
  const float* x = (const float*)d_in[0];
  float* out = (float*)d_out;
  // ws layout: ws1 = 128*8*4096 floats (16.78 MB), ws2bf = 128*4096 ushort (1 MB)
  float* ws1 = (float*)d_ws;
  unsigned short* ws2bf = (unsigned short*)(ws1 + (size_t)128 * NCHUNK * 4096);

  k1_kv_accum<<<128 * NCHUNK, 256, 0, stream>>>(x, ws1);
  k2_softmax<<<128, 256, 0, stream>>>(ws1, ws2bf);
  k3_apply<<<128 * 32, 256, 0, stream>>>(x, ws2bf, out);
}